// Round 4
// baseline (453.365 us; speedup 1.0000x reference)
//
#include <hip/hip_runtime.h>
#include <hip/hip_bf16.h>

#define NN 8192
#define EE 262144
#define DD 128
#define HH 64

#define GATE_BLOCKS (EE / 64)     // 4096 blocks, 64 edges each
#define FILL_BLOCKS 8192          // 32 KB of zeros each (268 MB total)
#define SCAT_BLOCKS (EE / 256)    // 1024 blocks, 1 thread per edge

// K1: Pt[n][j] = embed[n] . W1[0:128, j],  Pb[n][j] = embed[n] . W1[128:256, j]
__global__ void precompute_kernel(const float* __restrict__ embed,
                                  const float* __restrict__ W1,
                                  float* __restrict__ Pt,
                                  float* __restrict__ Pb) {
    const int tid  = threadIdx.x;
    const int w    = tid >> 6;
    const int lane = tid & 63;
    const int n    = (blockIdx.x << 2) + w;

    __shared__ float esh[4][DD];
    esh[w][lane]      = embed[n * DD + lane];
    esh[w][lane + 64] = embed[n * DD + 64 + lane];
    __syncthreads();

    float at = 0.f, ab = 0.f;
#pragma unroll 8
    for (int k = 0; k < DD; ++k) {
        float ek = esh[w][k];
        at = fmaf(ek, W1[k * HH + lane],        at);   // 256 B coalesced row
        ab = fmaf(ek, W1[(DD + k) * HH + lane], ab);
    }
    Pt[n * HH + lane] = at;
    Pb[n * HH + lane] = ab;
}

// K2: heterogeneous. Blocks [0, GATE_BLOCKS) compute g2[e] (gathers hit L2,
// hidden under the fill's HBM write BW); blocks [GATE_BLOCKS, +FILL_BLOCKS)
// stream 268 MB of zeros into the output.
__global__ void fill_gate_kernel(const float4* __restrict__ Pt4,
                                 const float4* __restrict__ Pb4,
                                 const float* __restrict__ b1,
                                 const float* __restrict__ W2,
                                 const float* __restrict__ b2,
                                 const float* __restrict__ noise,
                                 const int* __restrict__ ei,
                                 float* __restrict__ g2out,
                                 float4* __restrict__ out4) {
    const int tid = threadIdx.x;

    if (blockIdx.x >= GATE_BLOCKS) {                  // ---- fill path
        const size_t base = (size_t)(blockIdx.x - GATE_BLOCKS) * 2048 + tid;
        const float4 z = make_float4(0.f, 0.f, 0.f, 0.f);
#pragma unroll
        for (int i = 0; i < 8; ++i)
            out4[base + (size_t)i * 256] = z;
        return;
    }

    // ---- gate path: 64 edges per block, 16 lanes per edge
    const int lane = tid & 63;
    const int q    = lane & 15;
    const int g16  = lane >> 4;

    __shared__ int sflag;                              // int64-layout detect
    if (tid < 64) {
        int v = ei[2 * tid + 1];
        unsigned long long bal = __ballot(v != 0);
        if (tid == 0) sflag = (bal == 0ULL) ? 1 : 0;
    }
    __syncthreads();
    const bool i64 = (sflag != 0);

    const int ebase = (blockIdx.x << 6) + ((tid >> 6) << 4) + (g16 << 2);

    int r[4], c[4];
    if (i64) {
#pragma unroll
        for (int i = 0; i < 4; ++i) {
            r[i] = ei[2 * (ebase + i)];
            c[i] = ei[2 * (EE + ebase + i)];
        }
    } else {
#pragma unroll
        for (int i = 0; i < 4; ++i) {
            r[i] = ei[ebase + i];
            c[i] = ei[EE + ebase + i];
        }
    }

    const float4 bb = ((const float4*)b1)[q];
    const float4 ww = ((const float4*)W2)[q];

    float v[4];
#pragma unroll
    for (int i = 0; i < 4; ++i) {
        const float4 pt = Pt4[r[i] * 16 + q];
        const float4 pb = Pb4[c[i] * 16 + q];
        v[i] = fmaxf(pt.x + pb.x + bb.x, 0.f) * ww.x
             + fmaxf(pt.y + pb.y + bb.y, 0.f) * ww.y
             + fmaxf(pt.z + pb.z + bb.z, 0.f) * ww.z
             + fmaxf(pt.w + pb.w + bb.w, 0.f) * ww.w;
    }

#pragma unroll
    for (int i = 0; i < 4; ++i)
#pragma unroll
        for (int off = 8; off; off >>= 1)
            v[i] += __shfl_xor(v[i], off, 64);

    if (q == 0) {                                      // 4 leaders per wave
        const float bias2 = b2[0];
#pragma unroll
        for (int i = 0; i < 4; ++i) {
            const float u     = noise[ebase + i];
            const float logit = logf(u) - log1pf(-u) + v[i] + bias2;
            g2out[ebase + i]  = 0.5f / (1.f + expf(-logit));
        }
    }
}

// K3: pure scatter, one thread per edge. adj[r][c]==1 by construction for
// every listed edge; transpose term gated on adj[c][r] (nonzero ~0.4%).
__global__ void scatter_kernel(const float* __restrict__ g2in,
                               const int* __restrict__ ei,
                               const float* __restrict__ adj,
                               float* __restrict__ out) {
    const int tid = threadIdx.x;

    __shared__ int sflag;
    if (tid < 64) {
        int v = ei[2 * tid + 1];
        unsigned long long bal = __ballot(v != 0);
        if (tid == 0) sflag = (bal == 0ULL) ? 1 : 0;
    }
    __syncthreads();

    const int e = (blockIdx.x << 8) + tid;
    int r, c;
    if (sflag) {
        r = ei[2 * e];
        c = ei[2 * (EE + e)];
    } else {
        r = ei[e];
        c = ei[EE + e];
    }

    const float g2 = g2in[e];
    const float a  = adj[(size_t)c * NN + r];          // issue before atomics
    atomicAdd(&out[(size_t)r * NN + c], g2);
    if (a != 0.f)
        atomicAdd(&out[(size_t)c * NN + r], g2 * a);
}

extern "C" void kernel_launch(void* const* d_in, const int* in_sizes, int n_in,
                              void* d_out, int out_size, void* d_ws, size_t ws_size,
                              hipStream_t stream) {
    const float* embed = (const float*)d_in[0];
    const float* adj   = (const float*)d_in[1];
    const float* noise = (const float*)d_in[2];
    const float* W1    = (const float*)d_in[3];
    const float* b1    = (const float*)d_in[4];
    const float* W2    = (const float*)d_in[5];
    const float* b2    = (const float*)d_in[6];
    const int*   ei    = (const int*)d_in[7];
    float* out = (float*)d_out;

    float* Pt = (float*)d_ws;                          // 2 MB
    float* Pb = Pt + (size_t)NN * HH;                  // 2 MB
    float* g2 = Pb + (size_t)NN * HH;                  // 1 MB

    precompute_kernel<<<NN / 4, 256, 0, stream>>>(embed, W1, Pt, Pb);
    fill_gate_kernel<<<GATE_BLOCKS + FILL_BLOCKS, 256, 0, stream>>>(
        (const float4*)Pt, (const float4*)Pb, b1, W2, b2, noise, ei, g2,
        (float4*)out);
    scatter_kernel<<<SCAT_BLOCKS, 256, 0, stream>>>(g2, ei, adj, out);
}